// Round 1
// baseline (1531.607 us; speedup 1.0000x reference)
//
#include <hip/hip_runtime.h>

#define D_MODEL 512
#define N_HEADS 8
#define HEAD_DIM 64
#define D_FF 2048
#define SEQ 2048
#define BATCH 2
#define MROWS (BATCH * SEQ) /* 4096 */

// ---------------------------------------------------------------------------
// Tiled fp32 GEMM: C[M,N] = A[M,K] @ W[K,N] + bias, optional ReLU,
// optional split-head output layout [B,H,S,Dh].
// 64x64 tile, 256 threads, 4x4 accum per thread, 16-wide K tiles.
// ---------------------------------------------------------------------------
template <int OUT_HEADS, int RELU>
__global__ __launch_bounds__(256) void gemm_bias_k(
    const float* __restrict__ A, const float* __restrict__ W,
    const float* __restrict__ bias, float* __restrict__ C,
    int M, int N, int K)
{
    __shared__ float As[16][68]; // [k][m], pad 68 -> 16B-aligned rows, 2-way max
    __shared__ float Bs[16][68]; // [k][n]

    const int tid = threadIdx.x;
    const int tx = tid & 15;  // n direction
    const int ty = tid >> 4;  // m direction
    const int m0 = blockIdx.y * 64;
    const int n0 = blockIdx.x * 64;

    float acc[4][4] = {};

    for (int k0 = 0; k0 < K; k0 += 16) {
        #pragma unroll
        for (int l = 0; l < 4; ++l) {
            int idx = tid + l * 256;      // 0..1023
            int r = idx >> 4;             // 0..63 (m)
            int c = idx & 15;             // 0..15 (k)
            As[c][r] = A[(size_t)(m0 + r) * K + (k0 + c)];
        }
        #pragma unroll
        for (int l = 0; l < 4; ++l) {
            int idx = tid + l * 256;
            int r = idx >> 6;             // 0..15 (k)
            int c = idx & 63;             // 0..63 (n)
            Bs[r][c] = W[(size_t)(k0 + r) * N + (n0 + c)];
        }
        __syncthreads();

        #pragma unroll
        for (int kk = 0; kk < 16; ++kk) {
            float4 a4 = *(const float4*)&As[kk][ty * 4];
            float4 b4 = *(const float4*)&Bs[kk][tx * 4];
            float a[4] = {a4.x, a4.y, a4.z, a4.w};
            float b[4] = {b4.x, b4.y, b4.z, b4.w};
            #pragma unroll
            for (int i = 0; i < 4; ++i)
                #pragma unroll
                for (int j = 0; j < 4; ++j)
                    acc[i][j] = fmaf(a[i], b[j], acc[i][j]);
        }
        __syncthreads();
    }

    #pragma unroll
    for (int i = 0; i < 4; ++i) {
        int m = m0 + ty * 4 + i;
        int bb = m / SEQ;
        int s  = m - bb * SEQ;
        #pragma unroll
        for (int j = 0; j < 4; ++j) {
            int n = n0 + tx * 4 + j;
            float v = acc[i][j] + bias[n];
            if (RELU) v = fmaxf(v, 0.0f);
            if (OUT_HEADS) {
                int h  = n >> 6;   // HEAD_DIM = 64
                int dh = n & 63;
                C[(((size_t)(bb * N_HEADS + h)) * SEQ + s) * HEAD_DIM + dh] = v;
            } else {
                C[(size_t)m * N + n] = v;
            }
        }
    }
}

// ---------------------------------------------------------------------------
// Flash-style attention, fp32. Q/K/V in [B*H][S][64] layout.
// Block: 256 threads = 64 query rows x 4 key-split groups.
// Each thread: online softmax over 512 keys, q[64] + acc[64] in registers.
// K/V reads are wave-uniform (all 64 lanes of a wave share g) -> L1 broadcast.
// Output written in [B,S,D_MODEL] layout for the Wo GEMM.
// ---------------------------------------------------------------------------
__global__ __launch_bounds__(256) void attn_k(
    const float* __restrict__ Qg, const float* __restrict__ Kg,
    const float* __restrict__ Vg, float* __restrict__ ctx)
{
    const int bh = blockIdx.x;        // 0..15
    const int q0 = blockIdx.y * 64;   // query tile base
    const int t = threadIdx.x;
    const int r = t & 63;             // row within tile
    const int g = t >> 6;             // key group 0..3
    const int qrow = q0 + r;
    const int KEYS = SEQ / 4;         // 512 keys per group
    const int kbase = g * KEYS;

    float q[64];
    {
        const float4* q4 = (const float4*)(Qg + ((size_t)bh * SEQ + qrow) * HEAD_DIM);
        #pragma unroll
        for (int i = 0; i < 16; ++i) {
            float4 f = q4[i];
            q[4*i+0] = f.x * 0.125f;  // 1/sqrt(64) folded into q
            q[4*i+1] = f.y * 0.125f;
            q[4*i+2] = f.z * 0.125f;
            q[4*i+3] = f.w * 0.125f;
        }
    }

    float m = -1e30f, l = 0.0f;
    float acc[64];
    #pragma unroll
    for (int i = 0; i < 64; ++i) acc[i] = 0.0f;

    const float4* K4 = (const float4*)(Kg + ((size_t)bh * SEQ + kbase) * HEAD_DIM);
    const float4* V4 = (const float4*)(Vg + ((size_t)bh * SEQ + kbase) * HEAD_DIM);

    for (int j = 0; j < KEYS; ++j) {
        float s = 0.0f;
        #pragma unroll
        for (int i = 0; i < 16; ++i) {
            float4 kv = K4[j * 16 + i];
            s = fmaf(q[4*i+0], kv.x, s);
            s = fmaf(q[4*i+1], kv.y, s);
            s = fmaf(q[4*i+2], kv.z, s);
            s = fmaf(q[4*i+3], kv.w, s);
        }
        if (s > m) { // rescale only when running max changes (~log(n) times)
            float c = __expf(m - s);
            l *= c;
            #pragma unroll
            for (int i = 0; i < 64; ++i) acc[i] *= c;
            m = s;
        }
        float p = __expf(s - m);
        l += p;
        #pragma unroll
        for (int i = 0; i < 16; ++i) {
            float4 vv = V4[j * 16 + i];
            acc[4*i+0] = fmaf(p, vv.x, acc[4*i+0]);
            acc[4*i+1] = fmaf(p, vv.y, acc[4*i+1]);
            acc[4*i+2] = fmaf(p, vv.z, acc[4*i+2]);
            acc[4*i+3] = fmaf(p, vv.w, acc[4*i+3]);
        }
    }

    // combine the 4 key-split partials per row
    __shared__ float redm[4][64];
    __shared__ float redl[4][64];
    redm[g][r] = m;
    redl[g][r] = l;
    __syncthreads();
    float M2 = fmaxf(fmaxf(redm[0][r], redm[1][r]), fmaxf(redm[2][r], redm[3][r]));
    float L = 0.0f;
    #pragma unroll
    for (int gg = 0; gg < 4; ++gg) L += redl[gg][r] * __expf(redm[gg][r] - M2);
    const float w = __expf(m - M2) / L;

    __shared__ float obuf[64][65];
    if (g == 0) {
        #pragma unroll
        for (int i = 0; i < 64; ++i) obuf[r][i] = w * acc[i];
    }
    __syncthreads();
    if (g == 1) {
        #pragma unroll
        for (int i = 0; i < 64; ++i) obuf[r][i] += w * acc[i];
    }
    __syncthreads();
    if (g == 2) {
        #pragma unroll
        for (int i = 0; i < 64; ++i) obuf[r][i] += w * acc[i];
    }
    __syncthreads();
    if (g == 3) {
        #pragma unroll
        for (int i = 0; i < 64; ++i) obuf[r][i] += w * acc[i];
    }
    __syncthreads();

    const int bb = bh >> 3, hh = bh & 7;
    #pragma unroll
    for (int i = 0; i < 16; ++i) {
        int idx = t + i * 256;       // 0..4095
        int rr = idx >> 6, dd = idx & 63;
        ctx[((size_t)(bb * SEQ + q0 + rr)) * D_MODEL + hh * HEAD_DIM + dd] = obuf[rr][dd];
    }
}

// ---------------------------------------------------------------------------
// Residual + LayerNorm: O[row] = LN(X[row] + Y[row]) * gamma + beta
// One block (256 threads) per row of 512.
// ---------------------------------------------------------------------------
__global__ __launch_bounds__(256) void add_ln_k(
    const float* __restrict__ X, const float* __restrict__ Y,
    const float* __restrict__ gam, const float* __restrict__ bet,
    float* __restrict__ O)
{
    const int row = blockIdx.x;
    const int t = threadIdx.x;
    const float* x = X + (size_t)row * D_MODEL;
    const float* y = Y + (size_t)row * D_MODEL;

    float v0 = x[t] + y[t];
    float v1 = x[t + 256] + y[t + 256];
    float s = v0 + v1;
    float ss = v0 * v0 + v1 * v1;
    #pragma unroll
    for (int off = 32; off > 0; off >>= 1) {
        s  += __shfl_down(s, off);
        ss += __shfl_down(ss, off);
    }
    __shared__ float sb[4], ssb[4];
    if ((t & 63) == 0) { sb[t >> 6] = s; ssb[t >> 6] = ss; }
    __syncthreads();
    float S  = sb[0] + sb[1] + sb[2] + sb[3];
    float SS = ssb[0] + ssb[1] + ssb[2] + ssb[3];
    float mu  = S * (1.0f / D_MODEL);
    float var = SS * (1.0f / D_MODEL) - mu * mu;
    float inv = rsqrtf(var + 1e-5f);
    O[(size_t)row * D_MODEL + t]       = (v0 - mu) * inv * gam[t] + bet[t];
    O[(size_t)row * D_MODEL + t + 256] = (v1 - mu) * inv * gam[t + 256] + bet[t + 256];
}

// ---------------------------------------------------------------------------
extern "C" void kernel_launch(void* const* d_in, const int* in_sizes, int n_in,
                              void* d_out, int out_size, void* d_ws, size_t ws_size,
                              hipStream_t stream)
{
    const float* x   = (const float*)d_in[0];
    const float* Wq  = (const float*)d_in[1];
    const float* bq  = (const float*)d_in[2];
    const float* Wk  = (const float*)d_in[3];
    const float* bk  = (const float*)d_in[4];
    const float* Wv  = (const float*)d_in[5];
    const float* bv  = (const float*)d_in[6];
    const float* Wo  = (const float*)d_in[7];
    const float* bo  = (const float*)d_in[8];
    const float* W1  = (const float*)d_in[9];
    const float* b1  = (const float*)d_in[10];
    const float* W2  = (const float*)d_in[11];
    const float* b2  = (const float*)d_in[12];
    const float* g1  = (const float*)d_in[13];
    const float* be1 = (const float*)d_in[14];
    const float* g2  = (const float*)d_in[15];
    const float* be2 = (const float*)d_in[16];
    float* out = (float*)d_out;
    float* ws  = (float*)d_ws;

    const size_t CH = (size_t)MROWS * D_MODEL; // 2M floats
    float* Qb  = ws + 0 * CH;
    float* Kb  = ws + 1 * CH;
    float* Vb  = ws + 2 * CH;
    float* Ctx = ws + 3 * CH;
    float* FF1 = ws + 4 * CH;  // [4096, 2048] = 8M floats
    float* AO  = ws + 0 * CH;  // reuse Q (dead after attention)
    float* Hh  = ws + 1 * CH;  // reuse K
    float* FF2 = ws + 2 * CH;  // reuse V
    // total ws requirement: 12*CH floats = 64 MB

    dim3 blk(256);

    // QKV projections -> [B,H,S,Dh]
    gemm_bias_k<1, 0><<<dim3(D_MODEL / 64, MROWS / 64), blk, 0, stream>>>(
        x, Wq, bq, Qb, MROWS, D_MODEL, D_MODEL);
    gemm_bias_k<1, 0><<<dim3(D_MODEL / 64, MROWS / 64), blk, 0, stream>>>(
        x, Wk, bk, Kb, MROWS, D_MODEL, D_MODEL);
    gemm_bias_k<1, 0><<<dim3(D_MODEL / 64, MROWS / 64), blk, 0, stream>>>(
        x, Wv, bv, Vb, MROWS, D_MODEL, D_MODEL);

    // attention -> ctx in [B,S,D]
    attn_k<<<dim3(BATCH * N_HEADS, SEQ / 64), blk, 0, stream>>>(Qb, Kb, Vb, Ctx);

    // output projection
    gemm_bias_k<0, 0><<<dim3(D_MODEL / 64, MROWS / 64), blk, 0, stream>>>(
        Ctx, Wo, bo, AO, MROWS, D_MODEL, D_MODEL);

    // h = LN(x + attn_out)
    add_ln_k<<<dim3(MROWS), blk, 0, stream>>>(x, AO, g1, be1, Hh);

    // FFN
    gemm_bias_k<0, 1><<<dim3(D_FF / 64, MROWS / 64), blk, 0, stream>>>(
        Hh, W1, b1, FF1, MROWS, D_FF, D_MODEL);
    gemm_bias_k<0, 0><<<dim3(D_MODEL / 64, MROWS / 64), blk, 0, stream>>>(
        FF1, W2, b2, FF2, MROWS, D_MODEL, D_FF);

    // out = LN(h + ff)
    add_ln_k<<<dim3(MROWS), blk, 0, stream>>>(Hh, FF2, g2, be2, out);
}

// Round 2
// 586.823 us; speedup vs baseline: 2.6100x; 2.6100x over previous
//
#include <hip/hip_runtime.h>

#define D_MODEL 512
#define N_HEADS 8
#define HEAD_DIM 64
#define D_FF 2048
#define SEQ 2048
#define BATCH 2
#define MROWS (BATCH * SEQ) /* 4096 */

typedef __attribute__((ext_vector_type(8))) short short8;
typedef __attribute__((ext_vector_type(4))) float float4v;
typedef unsigned short ushort_t;

static __device__ inline ushort_t f2bf(float f) {
    union { float f; unsigned u; } v; v.f = f;
    unsigned r = (v.u + 0x7FFFu + ((v.u >> 16) & 1u)) >> 16;
    return (ushort_t)r;
}

// ---------------------------------------------------------------------------
// Tiled fp32 GEMM: C[M,N] = (A[M,K] @ W[K,N] + bias) * scale, optional ReLU.
// OUT_MODE: 0 = fp32 [M][N]
//           1 = bf16 split-head [BH][S][64]         (Q, K)
//           2 = bf16 split-head transposed [BH][64][S]  (V)
// 64x64 tile, 256 threads, 4x4 accum per thread, 16-wide K tiles.
// ---------------------------------------------------------------------------
template <int OUT_MODE, int RELU>
__global__ __launch_bounds__(256) void gemm_bias_k(
    const float* __restrict__ A, const float* __restrict__ W,
    const float* __restrict__ bias, void* __restrict__ Cv,
    int M, int N, int K, float scale)
{
    __shared__ float As[16][68];
    __shared__ float Bs[16][68];

    const int tid = threadIdx.x;
    const int tx = tid & 15;  // n direction
    const int ty = tid >> 4;  // m direction
    const int m0 = blockIdx.y * 64;
    const int n0 = blockIdx.x * 64;

    float acc[4][4] = {};

    for (int k0 = 0; k0 < K; k0 += 16) {
        #pragma unroll
        for (int l = 0; l < 4; ++l) {
            int idx = tid + l * 256;
            int r = idx >> 4;
            int c = idx & 15;
            As[c][r] = A[(size_t)(m0 + r) * K + (k0 + c)];
        }
        #pragma unroll
        for (int l = 0; l < 4; ++l) {
            int idx = tid + l * 256;
            int r = idx >> 6;
            int c = idx & 63;
            Bs[r][c] = W[(size_t)(k0 + r) * N + (n0 + c)];
        }
        __syncthreads();

        #pragma unroll
        for (int kk = 0; kk < 16; ++kk) {
            float4 a4 = *(const float4*)&As[kk][ty * 4];
            float4 b4 = *(const float4*)&Bs[kk][tx * 4];
            float a[4] = {a4.x, a4.y, a4.z, a4.w};
            float b[4] = {b4.x, b4.y, b4.z, b4.w};
            #pragma unroll
            for (int i = 0; i < 4; ++i)
                #pragma unroll
                for (int j = 0; j < 4; ++j)
                    acc[i][j] = fmaf(a[i], b[j], acc[i][j]);
        }
        __syncthreads();
    }

    #pragma unroll
    for (int i = 0; i < 4; ++i) {
        int m = m0 + ty * 4 + i;
        int bb = m / SEQ;
        int s  = m - bb * SEQ;
        #pragma unroll
        for (int j = 0; j < 4; ++j) {
            int n = n0 + tx * 4 + j;
            float v = (acc[i][j] + bias[n]) * scale;
            if (RELU) v = fmaxf(v, 0.0f);
            if (OUT_MODE == 0) {
                ((float*)Cv)[(size_t)m * N + n] = v;
            } else if (OUT_MODE == 1) {
                int h  = n >> 6;
                int dh = n & 63;
                ((ushort_t*)Cv)[(((size_t)(bb * N_HEADS + h)) * SEQ + s) * HEAD_DIM + dh] = f2bf(v);
            } else {
                int h  = n >> 6;
                int dh = n & 63;
                ((ushort_t*)Cv)[(((size_t)(bb * N_HEADS + h)) * HEAD_DIM + dh) * SEQ + s] = f2bf(v);
            }
        }
    }
}

// ---------------------------------------------------------------------------
// bf16 MFMA flash attention.
// Q,K bf16 [BH][S][64] (Q pre-scaled by 1/8); V bf16 transposed [BH][64][S].
// Block: 256 threads = 4 waves; each wave owns 16 query rows (64 per block).
// Loop over 32 key-tiles of 64 keys: stage K-tile + Vt-tile in LDS,
// S = Q·K^T via 8 MFMAs, online softmax (16-lane shfl reductions),
// P -> per-wave LDS (bf16), O += P·V via 8 MFMAs.
// MFMA 16x16x32 bf16 layouts (measured m89/m120):
//   C/D: col = lane&15, row = (lane>>4)*4 + reg
//   A:   m = lane&15,  k = (lane>>4)*8 + j
//   B:   n = lane&15,  k = (lane>>4)*8 + j
// Output ctx fp32 [B][S][512].
// ---------------------------------------------------------------------------
__global__ __launch_bounds__(256) void attn_mfma_k(
    const ushort_t* __restrict__ Qg, const ushort_t* __restrict__ Kg,
    const ushort_t* __restrict__ VTg, float* __restrict__ ctx)
{
    __shared__ __align__(16) ushort_t Ks[64 * 72];      // [key][d], pad 8 -> 2-way max
    __shared__ __align__(16) ushort_t Vs[64 * 72];      // [d][key], pad 8
    __shared__ __align__(16) ushort_t Ps[4][16 * 72];   // per-wave P tile [qrow][key]

    const int bh = blockIdx.x;          // 0..15
    const int q0 = blockIdx.y * 64;
    const int t = threadIdx.x;
    const int w = t >> 6;               // wave id 0..3
    const int lane = t & 63;
    const int l16 = lane & 15;
    const int quad = lane >> 4;
    const int qbase = q0 + w * 16;

    // Q A-fragments for both 32-wide d-chunks (held for the whole kernel)
    short8 aq[2];
    {
        const ushort_t* qp = Qg + ((size_t)bh * SEQ + qbase + l16) * HEAD_DIM + quad * 8;
        aq[0] = *(const short8*)(qp);
        aq[1] = *(const short8*)(qp + 32);
    }

    float4v o[4] = {};                  // O accum: 4 d-subtiles x 4 rows
    float m_r[4], l_r[4];
    #pragma unroll
    for (int r = 0; r < 4; ++r) { m_r[r] = -1e30f; l_r[r] = 0.0f; }

    for (int kt = 0; kt < 32; ++kt) {
        const int kbase = kt * 64;
        __syncthreads();  // previous iteration's LDS reads done before overwrite
        #pragma unroll
        for (int lit = 0; lit < 2; ++lit) {
            int flat = lit * 256 + t;   // 0..511
            int row = flat >> 3;        // 0..63
            int c0 = (flat & 7) * 8;    // 0..56
            *(short8*)&Ks[row * 72 + c0] =
                *(const short8*)(Kg + ((size_t)bh * SEQ + kbase + row) * HEAD_DIM + c0);
            *(short8*)&Vs[row * 72 + c0] =
                *(const short8*)(VTg + ((size_t)bh * HEAD_DIM + row) * SEQ + kbase + c0);
        }
        __syncthreads();

        // S = Q · K^T  (16 q-rows x 64 keys, 4 subtiles x 2 k-chunks)
        float4v s[4];
        #pragma unroll
        for (int nt = 0; nt < 4; ++nt) s[nt] = (float4v){0.f, 0.f, 0.f, 0.f};
        #pragma unroll
        for (int c = 0; c < 2; ++c) {
            #pragma unroll
            for (int nt = 0; nt < 4; ++nt) {
                short8 bk = *(const short8*)&Ks[(nt * 16 + l16) * 72 + c * 32 + quad * 8];
                s[nt] = __builtin_amdgcn_mfma_f32_16x16x32_bf16(aq[c], bk, s[nt], 0, 0, 0);
            }
        }

        // online softmax per row (rows replicated across the 16-lane group)
        float alpha[4];
        #pragma unroll
        for (int r = 0; r < 4; ++r) {
            float mx = fmaxf(fmaxf(s[0][r], s[1][r]), fmaxf(s[2][r], s[3][r]));
            #pragma unroll
            for (int msk = 1; msk < 16; msk <<= 1) mx = fmaxf(mx, __shfl_xor(mx, msk));
            float mnew = fmaxf(m_r[r], mx);
            alpha[r] = __expf(m_r[r] - mnew);
            m_r[r] = mnew;
            float sum = 0.0f;
            #pragma unroll
            for (int nt = 0; nt < 4; ++nt) {
                float p = __expf(s[nt][r] - mnew);
                s[nt][r] = p;
                sum += p;
            }
            #pragma unroll
            for (int msk = 1; msk < 16; msk <<= 1) sum += __shfl_xor(sum, msk);
            l_r[r] = l_r[r] * alpha[r] + sum;
        }

        // write P (C/D layout -> [qrow][key] in per-wave LDS), rescale O
        #pragma unroll
        for (int nt = 0; nt < 4; ++nt)
            #pragma unroll
            for (int r = 0; r < 4; ++r)
                Ps[w][(quad * 4 + r) * 72 + nt * 16 + l16] = f2bf(s[nt][r]);
        #pragma unroll
        for (int dt = 0; dt < 4; ++dt)
            #pragma unroll
            for (int r = 0; r < 4; ++r)
                o[dt][r] *= alpha[r];
        asm volatile("s_waitcnt lgkmcnt(0)" ::: "memory");  // wave-private Ps visible

        // O += P · V  (contraction over 64 keys = 2 chunks; 4 d-subtiles)
        #pragma unroll
        for (int c = 0; c < 2; ++c) {
            short8 ap = *(const short8*)&Ps[w][l16 * 72 + c * 32 + quad * 8];
            #pragma unroll
            for (int dt = 0; dt < 4; ++dt) {
                short8 bv = *(const short8*)&Vs[(dt * 16 + l16) * 72 + c * 32 + quad * 8];
                o[dt] = __builtin_amdgcn_mfma_f32_16x16x32_bf16(ap, bv, o[dt], 0, 0, 0);
            }
        }
    }

    // epilogue: normalize and write ctx fp32 [B][S][512]
    const int bb = bh >> 3, hh = bh & 7;
    #pragma unroll
    for (int r = 0; r < 4; ++r) {
        float inv = 1.0f / l_r[r];
        size_t rowoff = ((size_t)(bb * SEQ + qbase + quad * 4 + r)) * D_MODEL + hh * HEAD_DIM;
        #pragma unroll
        for (int dt = 0; dt < 4; ++dt)
            ctx[rowoff + dt * 16 + l16] = o[dt][r] * inv;
    }
}

// ---------------------------------------------------------------------------
// Residual + LayerNorm: O[row] = LN(X[row] + Y[row]) * gamma + beta
// ---------------------------------------------------------------------------
__global__ __launch_bounds__(256) void add_ln_k(
    const float* __restrict__ X, const float* __restrict__ Y,
    const float* __restrict__ gam, const float* __restrict__ bet,
    float* __restrict__ O)
{
    const int row = blockIdx.x;
    const int t = threadIdx.x;
    const float* x = X + (size_t)row * D_MODEL;
    const float* y = Y + (size_t)row * D_MODEL;

    float v0 = x[t] + y[t];
    float v1 = x[t + 256] + y[t + 256];
    float s = v0 + v1;
    float ss = v0 * v0 + v1 * v1;
    #pragma unroll
    for (int off = 32; off > 0; off >>= 1) {
        s  += __shfl_down(s, off);
        ss += __shfl_down(ss, off);
    }
    __shared__ float sb[4], ssb[4];
    if ((t & 63) == 0) { sb[t >> 6] = s; ssb[t >> 6] = ss; }
    __syncthreads();
    float S  = sb[0] + sb[1] + sb[2] + sb[3];
    float SS = ssb[0] + ssb[1] + ssb[2] + ssb[3];
    float mu  = S * (1.0f / D_MODEL);
    float var = SS * (1.0f / D_MODEL) - mu * mu;
    float inv = rsqrtf(var + 1e-5f);
    O[(size_t)row * D_MODEL + t]       = (v0 - mu) * inv * gam[t] + bet[t];
    O[(size_t)row * D_MODEL + t + 256] = (v1 - mu) * inv * gam[t + 256] + bet[t + 256];
}

// ---------------------------------------------------------------------------
extern "C" void kernel_launch(void* const* d_in, const int* in_sizes, int n_in,
                              void* d_out, int out_size, void* d_ws, size_t ws_size,
                              hipStream_t stream)
{
    const float* x   = (const float*)d_in[0];
    const float* Wq  = (const float*)d_in[1];
    const float* bq  = (const float*)d_in[2];
    const float* Wk  = (const float*)d_in[3];
    const float* bk  = (const float*)d_in[4];
    const float* Wv  = (const float*)d_in[5];
    const float* bv  = (const float*)d_in[6];
    const float* Wo  = (const float*)d_in[7];
    const float* bo  = (const float*)d_in[8];
    const float* W1  = (const float*)d_in[9];
    const float* b1  = (const float*)d_in[10];
    const float* W2  = (const float*)d_in[11];
    const float* b2  = (const float*)d_in[12];
    const float* g1  = (const float*)d_in[13];
    const float* be1 = (const float*)d_in[14];
    const float* g2  = (const float*)d_in[15];
    const float* be2 = (const float*)d_in[16];
    float* out = (float*)d_out;
    float* ws  = (float*)d_ws;

    const size_t CH = (size_t)MROWS * D_MODEL; // 2M floats
    ushort_t* Qb  = (ushort_t*)(ws + 0 * CH);  // bf16, uses half the slot
    ushort_t* Kb  = (ushort_t*)(ws + 1 * CH);
    ushort_t* VTb = (ushort_t*)(ws + 2 * CH);  // transposed [BH][64][S]
    float* Ctx = ws + 3 * CH;
    float* FF1 = ws + 4 * CH;                  // [4096, 2048] = 8M floats
    float* AO  = ws + 0 * CH;                  // reuse (Qb dead after attention)
    float* Hh  = ws + 1 * CH;                  // reuse (Kb dead)
    float* FF2 = ws + 2 * CH;                  // reuse (VTb dead)

    dim3 blk(256);

    // QKV projections -> bf16 head layouts (Q pre-scaled by 1/sqrt(64))
    gemm_bias_k<1, 0><<<dim3(D_MODEL / 64, MROWS / 64), blk, 0, stream>>>(
        x, Wq, bq, Qb, MROWS, D_MODEL, D_MODEL, 0.125f);
    gemm_bias_k<1, 0><<<dim3(D_MODEL / 64, MROWS / 64), blk, 0, stream>>>(
        x, Wk, bk, Kb, MROWS, D_MODEL, D_MODEL, 1.0f);
    gemm_bias_k<2, 0><<<dim3(D_MODEL / 64, MROWS / 64), blk, 0, stream>>>(
        x, Wv, bv, VTb, MROWS, D_MODEL, D_MODEL, 1.0f);

    // MFMA flash attention -> ctx fp32 [B,S,D]
    attn_mfma_k<<<dim3(BATCH * N_HEADS, SEQ / 64), blk, 0, stream>>>(Qb, Kb, VTb, Ctx);

    // output projection
    gemm_bias_k<0, 0><<<dim3(D_MODEL / 64, MROWS / 64), blk, 0, stream>>>(
        Ctx, Wo, bo, AO, MROWS, D_MODEL, D_MODEL, 1.0f);

    // h = LN(x + attn_out)
    add_ln_k<<<dim3(MROWS), blk, 0, stream>>>(x, AO, g1, be1, Hh);

    // FFN
    gemm_bias_k<0, 1><<<dim3(D_FF / 64, MROWS / 64), blk, 0, stream>>>(
        Hh, W1, b1, FF1, MROWS, D_FF, D_MODEL, 1.0f);
    gemm_bias_k<0, 0><<<dim3(D_MODEL / 64, MROWS / 64), blk, 0, stream>>>(
        FF1, W2, b2, FF2, MROWS, D_MODEL, D_FF, 1.0f);

    // out = LN(h + ff)
    add_ln_k<<<dim3(MROWS), blk, 0, stream>>>(Hh, FF2, g2, be2, out);
}

// Round 3
// 279.914 us; speedup vs baseline: 5.4717x; 2.0964x over previous
//
#include <hip/hip_runtime.h>

#define D_MODEL 512
#define N_HEADS 8
#define HEAD_DIM 64
#define D_FF 2048
#define SEQ 2048
#define BATCH 2
#define MROWS (BATCH * SEQ) /* 4096 */

typedef __attribute__((ext_vector_type(8))) short short8;
typedef __attribute__((ext_vector_type(4))) float float4v;
typedef unsigned short ushort_t;

static __device__ __forceinline__ ushort_t f2bf(float f) {
    union { float f; unsigned u; } v; v.f = f;
    unsigned r = (v.u + 0x7FFFu + ((v.u >> 16) & 1u)) >> 16;
    return (ushort_t)r;
}

// async global->LDS, 16B per lane; LDS dest = wave-uniform base + lane*16
static __device__ __forceinline__ void gload16(const void* g, void* l) {
    __builtin_amdgcn_global_load_lds(
        (__attribute__((address_space(1))) void*)(unsigned long long)g,
        (__attribute__((address_space(3))) void*)(unsigned)(unsigned long long)l,
        16, 0, 0);
}

// ---------------------------------------------------------------------------
// x fp32 -> bf16 (same [M][K] layout)
// ---------------------------------------------------------------------------
__global__ __launch_bounds__(256) void xbf_k(const float* __restrict__ x,
                                             ushort_t* __restrict__ xb)
{
    int i = blockIdx.x * 256 + threadIdx.x;   // covers 2M/4 elements
    float4 f = ((const float4*)x)[i];
    ushort4 o;
    o.x = f2bf(f.x); o.y = f2bf(f.y); o.z = f2bf(f.z); o.w = f2bf(f.w);
    ((ushort4*)xb)[i] = o;
}

// ---------------------------------------------------------------------------
// Weight transpose+convert: W[K][N] fp32 -> WT[N][K] bf16, 32x32 LDS tiles.
// One launch handles Wq,Wk,Wv (into concatenated WqkvT[1536][512]), Wo, W1, W2.
// ---------------------------------------------------------------------------
__global__ __launch_bounds__(256) void wt_k(
    const float* __restrict__ Wq, const float* __restrict__ Wk,
    const float* __restrict__ Wv, const float* __restrict__ Wo,
    const float* __restrict__ W1, const float* __restrict__ W2,
    ushort_t* __restrict__ WqkvT, ushort_t* __restrict__ WoT,
    ushort_t* __restrict__ W1T, ushort_t* __restrict__ W2T)
{
    int tile = blockIdx.x;                 // 0..3071
    const float* src; ushort_t* dst; int Kd, Nd, tloc;
    if (tile < 1024) {
        int wsel = tile >> 8; tloc = tile & 255; Kd = 512; Nd = 512;
        if (wsel == 0)      { src = Wq; dst = WqkvT; }
        else if (wsel == 1) { src = Wk; dst = WqkvT + (size_t)512 * 512; }
        else if (wsel == 2) { src = Wv; dst = WqkvT + (size_t)1024 * 512; }
        else                { src = Wo; dst = WoT; }
    } else if (tile < 2048) { tloc = tile - 1024; Kd = 512;  Nd = 2048; src = W1; dst = W1T; }
    else                    { tloc = tile - 2048; Kd = 2048; Nd = 512;  src = W2; dst = W2T; }
    int tn = Nd >> 5;
    int k0 = (tloc / tn) << 5, n0 = (tloc % tn) << 5;
    __shared__ float tl[32][33];
    int c = threadIdx.x & 31, r = threadIdx.x >> 5;
    #pragma unroll
    for (int i = 0; i < 4; ++i)
        tl[r + i * 8][c] = src[(size_t)(k0 + r + i * 8) * Nd + n0 + c];
    __syncthreads();
    #pragma unroll
    for (int i = 0; i < 4; ++i)
        dst[(size_t)(n0 + r + i * 8) * Kd + k0 + c] = f2bf(tl[c][r + i * 8]);
}

// ---------------------------------------------------------------------------
// MFMA bf16 GEMM core (m97 recipe): C[128 x BN] += A[M,K]bf16 @ BT[N,K]bf16^T.
// BK=32, LDS unpadded [row][k] (global_load_lds-contiguous), 4 waves.
// BN=128: wave grid 2x2, wave tile 64x64 (MT=4). BN=64: 4x1, 32x64 (MT=2).
// Fragment layouts (measured m89): A/B: idx16=lane&15, k=quad*8+j;
// C/D: col=lane&15, row=quad*4+reg.
// ---------------------------------------------------------------------------
template <int BN, int MT>
__device__ __forceinline__ void gemm_core(
    const ushort_t* __restrict__ A, const ushort_t* __restrict__ BT,
    int K, int m0, int n0, float4v (&acc)[MT][4])
{
    __shared__ ushort_t As[128 * 32];
    __shared__ ushort_t Bs[BN * 32];

    const int t = threadIdx.x;
    const int w = t >> 6;
    const int lane = t & 63;
    const int l16 = lane & 15;
    const int quad = lane >> 4;
    constexpr int WCOLS = (BN == 128) ? 2 : 1;
    const int mbase = (w / WCOLS) * (MT * 16);
    const int nbase = (w % WCOLS) * 64;
    const int lr = lane >> 2;        // row within 16-row chunk
    const int lc = (lane & 3) * 8;   // k element offset

    for (int k0 = 0; k0 < K; k0 += 32) {
        __syncthreads();   // previous iter's ds_reads drained before overwrite
        for (int c = w; c < 8; c += 4)
            gload16(A + (size_t)(m0 + c * 16 + lr) * K + k0 + lc, &As[c * 512]);
        for (int c = w; c < BN / 16; c += 4)
            gload16(BT + (size_t)(n0 + c * 16 + lr) * K + k0 + lc, &Bs[c * 512]);
        __syncthreads();   // vmcnt(0) drain: staging visible

        short8 af[MT], bfr[4];
        #pragma unroll
        for (int mt = 0; mt < MT; ++mt)
            af[mt] = *(const short8*)&As[(mbase + mt * 16 + l16) * 32 + quad * 8];
        #pragma unroll
        for (int nt = 0; nt < 4; ++nt)
            bfr[nt] = *(const short8*)&Bs[(nbase + nt * 16 + l16) * 32 + quad * 8];
        #pragma unroll
        for (int mt = 0; mt < MT; ++mt)
            #pragma unroll
            for (int nt = 0; nt < 4; ++nt)
                acc[mt][nt] = __builtin_amdgcn_mfma_f32_16x16x32_bf16(
                    af[mt], bfr[nt], acc[mt][nt], 0, 0, 0);
    }
}

// ---------------------------------------------------------------------------
// Standard GEMM: out = A @ BT^T + bias, fp32 or bf16 out, optional ReLU.
// ---------------------------------------------------------------------------
template <int BN, int MT, int BF16OUT, int RELU>
__global__ __launch_bounds__(256) void gemm_std_k(
    const ushort_t* __restrict__ A, const ushort_t* __restrict__ BT,
    const float* __restrict__ bias, void* __restrict__ Cv, int N, int K)
{
    const int m0 = blockIdx.y * 128;
    const int n0 = blockIdx.x * BN;
    float4v acc[MT][4];
    #pragma unroll
    for (int mt = 0; mt < MT; ++mt)
        #pragma unroll
        for (int nt = 0; nt < 4; ++nt)
            acc[mt][nt] = (float4v){0.f, 0.f, 0.f, 0.f};
    gemm_core<BN, MT>(A, BT, K, m0, n0, acc);

    const int t = threadIdx.x;
    const int w = t >> 6, lane = t & 63, l16 = lane & 15, quad = lane >> 4;
    constexpr int WCOLS = (BN == 128) ? 2 : 1;
    const int mbase = (w / WCOLS) * (MT * 16);
    const int nbase = (w % WCOLS) * 64;
    #pragma unroll
    for (int mt = 0; mt < MT; ++mt) {
        #pragma unroll
        for (int nt = 0; nt < 4; ++nt) {
            int gcol = n0 + nbase + nt * 16 + l16;
            float b = bias[gcol];
            #pragma unroll
            for (int r = 0; r < 4; ++r) {
                int grow = m0 + mbase + mt * 16 + quad * 4 + r;
                float v = acc[mt][nt][r] + b;
                if (RELU) v = fmaxf(v, 0.f);
                if (BF16OUT) ((ushort_t*)Cv)[(size_t)grow * N + gcol] = f2bf(v);
                else         ((float*)Cv)[(size_t)grow * N + gcol] = v;
            }
        }
    }
}

// ---------------------------------------------------------------------------
// Fused QKV GEMM: A[4096,512]bf16 @ WqkvT[1536,512]^T. Block-uniform epilogue
// select (512 % 128 == 0): Q (scaled 1/8) / K -> [BH][S][64]; V -> [BH][64][S].
// ---------------------------------------------------------------------------
__global__ __launch_bounds__(256) void gemm_qkv_k(
    const ushort_t* __restrict__ A, const ushort_t* __restrict__ BT,
    const float* __restrict__ bq, const float* __restrict__ bk,
    const float* __restrict__ bv,
    ushort_t* __restrict__ Qb, ushort_t* __restrict__ Kb,
    ushort_t* __restrict__ VTb)
{
    const int m0 = blockIdx.y * 128;
    const int n0 = blockIdx.x * 128;
    float4v acc[4][4];
    #pragma unroll
    for (int mt = 0; mt < 4; ++mt)
        #pragma unroll
        for (int nt = 0; nt < 4; ++nt)
            acc[mt][nt] = (float4v){0.f, 0.f, 0.f, 0.f};
    gemm_core<128, 4>(A, BT, 512, m0, n0, acc);

    const int t = threadIdx.x;
    const int w = t >> 6, lane = t & 63, l16 = lane & 15, quad = lane >> 4;
    const int mbase = (w >> 1) * 64;
    const int nbase = (w & 1) * 64;
    const int tsel = n0 >> 9;                       // 0=Q 1=K 2=V (block-uniform)
    const float* bias = (tsel == 0) ? bq : (tsel == 1) ? bk : bv;
    const float scl = (tsel == 0) ? 0.125f : 1.0f;  // fold 1/sqrt(64) into Q
    ushort_t* dst = (tsel == 0) ? Qb : Kb;

    #pragma unroll
    for (int mt = 0; mt < 4; ++mt) {
        #pragma unroll
        for (int nt = 0; nt < 4; ++nt) {
            int gcol = n0 + nbase + nt * 16 + l16;
            int lcol = gcol - (tsel << 9);
            int h = lcol >> 6, dh = lcol & 63;
            float b = bias[lcol];
            #pragma unroll
            for (int r = 0; r < 4; ++r) {
                int grow = m0 + mbase + mt * 16 + quad * 4 + r;
                int bb = grow >> 11, s = grow & 2047;
                float v = (acc[mt][nt][r] + b) * scl;
                if (tsel < 2)
                    dst[(((size_t)(bb * N_HEADS + h)) * SEQ + s) * HEAD_DIM + dh] = f2bf(v);
                else
                    VTb[(((size_t)(bb * N_HEADS + h)) * HEAD_DIM + dh) * SEQ + s] = f2bf(v);
            }
        }
    }
}

// ---------------------------------------------------------------------------
// bf16 MFMA flash attention (round-2, unchanged except bf16 ctx output).
// ---------------------------------------------------------------------------
__global__ __launch_bounds__(256) void attn_mfma_k(
    const ushort_t* __restrict__ Qg, const ushort_t* __restrict__ Kg,
    const ushort_t* __restrict__ VTg, ushort_t* __restrict__ ctx)
{
    __shared__ __align__(16) ushort_t Ks[64 * 72];
    __shared__ __align__(16) ushort_t Vs[64 * 72];
    __shared__ __align__(16) ushort_t Ps[4][16 * 72];

    const int bh = blockIdx.x;
    const int q0 = blockIdx.y * 64;
    const int t = threadIdx.x;
    const int w = t >> 6;
    const int lane = t & 63;
    const int l16 = lane & 15;
    const int quad = lane >> 4;
    const int qbase = q0 + w * 16;

    short8 aq[2];
    {
        const ushort_t* qp = Qg + ((size_t)bh * SEQ + qbase + l16) * HEAD_DIM + quad * 8;
        aq[0] = *(const short8*)(qp);
        aq[1] = *(const short8*)(qp + 32);
    }

    float4v o[4] = {};
    float m_r[4], l_r[4];
    #pragma unroll
    for (int r = 0; r < 4; ++r) { m_r[r] = -1e30f; l_r[r] = 0.0f; }

    for (int kt = 0; kt < 32; ++kt) {
        const int kbase = kt * 64;
        __syncthreads();
        #pragma unroll
        for (int lit = 0; lit < 2; ++lit) {
            int flat = lit * 256 + t;
            int row = flat >> 3;
            int c0 = (flat & 7) * 8;
            *(short8*)&Ks[row * 72 + c0] =
                *(const short8*)(Kg + ((size_t)bh * SEQ + kbase + row) * HEAD_DIM + c0);
            *(short8*)&Vs[row * 72 + c0] =
                *(const short8*)(VTg + ((size_t)bh * HEAD_DIM + row) * SEQ + kbase + c0);
        }
        __syncthreads();

        float4v s[4];
        #pragma unroll
        for (int nt = 0; nt < 4; ++nt) s[nt] = (float4v){0.f, 0.f, 0.f, 0.f};
        #pragma unroll
        for (int c = 0; c < 2; ++c) {
            #pragma unroll
            for (int nt = 0; nt < 4; ++nt) {
                short8 bk8 = *(const short8*)&Ks[(nt * 16 + l16) * 72 + c * 32 + quad * 8];
                s[nt] = __builtin_amdgcn_mfma_f32_16x16x32_bf16(aq[c], bk8, s[nt], 0, 0, 0);
            }
        }

        float alpha[4];
        #pragma unroll
        for (int r = 0; r < 4; ++r) {
            float mx = fmaxf(fmaxf(s[0][r], s[1][r]), fmaxf(s[2][r], s[3][r]));
            #pragma unroll
            for (int msk = 1; msk < 16; msk <<= 1) mx = fmaxf(mx, __shfl_xor(mx, msk));
            float mnew = fmaxf(m_r[r], mx);
            alpha[r] = __expf(m_r[r] - mnew);
            m_r[r] = mnew;
            float sum = 0.0f;
            #pragma unroll
            for (int nt = 0; nt < 4; ++nt) {
                float p = __expf(s[nt][r] - mnew);
                s[nt][r] = p;
                sum += p;
            }
            #pragma unroll
            for (int msk = 1; msk < 16; msk <<= 1) sum += __shfl_xor(sum, msk);
            l_r[r] = l_r[r] * alpha[r] + sum;
        }

        #pragma unroll
        for (int nt = 0; nt < 4; ++nt)
            #pragma unroll
            for (int r = 0; r < 4; ++r)
                Ps[w][(quad * 4 + r) * 72 + nt * 16 + l16] = f2bf(s[nt][r]);
        #pragma unroll
        for (int dt = 0; dt < 4; ++dt)
            #pragma unroll
            for (int r = 0; r < 4; ++r)
                o[dt][r] *= alpha[r];
        asm volatile("s_waitcnt lgkmcnt(0)" ::: "memory");

        #pragma unroll
        for (int c = 0; c < 2; ++c) {
            short8 ap = *(const short8*)&Ps[w][l16 * 72 + c * 32 + quad * 8];
            #pragma unroll
            for (int dt = 0; dt < 4; ++dt) {
                short8 bv8 = *(const short8*)&Vs[(dt * 16 + l16) * 72 + c * 32 + quad * 8];
                o[dt] = __builtin_amdgcn_mfma_f32_16x16x32_bf16(ap, bv8, o[dt], 0, 0, 0);
            }
        }
    }

    const int bb = bh >> 3, hh = bh & 7;
    #pragma unroll
    for (int r = 0; r < 4; ++r) {
        float inv = 1.0f / l_r[r];
        size_t rowoff = ((size_t)(bb * SEQ + qbase + quad * 4 + r)) * D_MODEL + hh * HEAD_DIM;
        #pragma unroll
        for (int dt = 0; dt < 4; ++dt)
            ctx[rowoff + dt * 16 + l16] = f2bf(o[dt][r] * inv);
    }
}

// ---------------------------------------------------------------------------
// Residual + LayerNorm; optional bf16 copy of the output (next GEMM's A).
// ---------------------------------------------------------------------------
template <int WRITE_BF>
__global__ __launch_bounds__(256) void add_ln_k(
    const float* __restrict__ X, const float* __restrict__ Y,
    const float* __restrict__ gam, const float* __restrict__ bet,
    float* __restrict__ O, ushort_t* __restrict__ Ob)
{
    const int row = blockIdx.x;
    const int t = threadIdx.x;
    const float* x = X + (size_t)row * D_MODEL;
    const float* y = Y + (size_t)row * D_MODEL;

    float v0 = x[t] + y[t];
    float v1 = x[t + 256] + y[t + 256];
    float s = v0 + v1;
    float ss = v0 * v0 + v1 * v1;
    #pragma unroll
    for (int off = 32; off > 0; off >>= 1) {
        s  += __shfl_down(s, off);
        ss += __shfl_down(ss, off);
    }
    __shared__ float sb[4], ssb[4];
    if ((t & 63) == 0) { sb[t >> 6] = s; ssb[t >> 6] = ss; }
    __syncthreads();
    float S  = sb[0] + sb[1] + sb[2] + sb[3];
    float SS = ssb[0] + ssb[1] + ssb[2] + ssb[3];
    float mu  = S * (1.0f / D_MODEL);
    float var = SS * (1.0f / D_MODEL) - mu * mu;
    float inv = rsqrtf(var + 1e-5f);
    float o0 = (v0 - mu) * inv * gam[t] + bet[t];
    float o1 = (v1 - mu) * inv * gam[t + 256] + bet[t + 256];
    O[(size_t)row * D_MODEL + t]       = o0;
    O[(size_t)row * D_MODEL + t + 256] = o1;
    if (WRITE_BF) {
        Ob[(size_t)row * D_MODEL + t]       = f2bf(o0);
        Ob[(size_t)row * D_MODEL + t + 256] = f2bf(o1);
    }
}

// ---------------------------------------------------------------------------
extern "C" void kernel_launch(void* const* d_in, const int* in_sizes, int n_in,
                              void* d_out, int out_size, void* d_ws, size_t ws_size,
                              hipStream_t stream)
{
    const float* x   = (const float*)d_in[0];
    const float* Wq  = (const float*)d_in[1];
    const float* bq  = (const float*)d_in[2];
    const float* Wk  = (const float*)d_in[3];
    const float* bk  = (const float*)d_in[4];
    const float* Wv  = (const float*)d_in[5];
    const float* bv  = (const float*)d_in[6];
    const float* Wo  = (const float*)d_in[7];
    const float* bo  = (const float*)d_in[8];
    const float* W1  = (const float*)d_in[9];
    const float* b1  = (const float*)d_in[10];
    const float* W2  = (const float*)d_in[11];
    const float* b2  = (const float*)d_in[12];
    const float* g1  = (const float*)d_in[13];
    const float* be1 = (const float*)d_in[14];
    const float* g2  = (const float*)d_in[15];
    const float* be2 = (const float*)d_in[16];
    float* out = (float*)d_out;
    float* ws  = (float*)d_ws;

    // float-unit offsets (total 15204352 floats = 60.8 MB)
    ushort_t* xb    = (ushort_t*)(ws);               // [4096][512] bf16
    ushort_t* WqkvT = (ushort_t*)(ws + 1048576);     // [1536][512] bf16
    ushort_t* WoT   = (ushort_t*)(ws + 1441792);     // [512][512]
    ushort_t* W1T   = (ushort_t*)(ws + 1572864);     // [2048][512]
    ushort_t* W2T   = (ushort_t*)(ws + 2097152);     // [512][2048]
    ushort_t* Qb    = (ushort_t*)(ws + 2621440);     // [16][2048][64]
    ushort_t* Kb    = (ushort_t*)(ws + 3670016);
    ushort_t* VTb   = (ushort_t*)(ws + 4718592);     // [16][64][2048]
    ushort_t* Ctx   = (ushort_t*)(ws + 5767168);     // [4096][512] bf16
    float*    AO    = ws + 2621440;                  // fp32, over Qb+Kb (dead)
    ushort_t* Hhb   = (ushort_t*)(ws + 4718592);     // bf16, over VTb (dead)
    float*    Hh    = ws + 6815744;                  // fp32 [4096][512]
    float*    FF2   = ws + 8912896;                  // fp32 [4096][512]
    ushort_t* FF1   = (ushort_t*)(ws + 11010048);    // bf16 [4096][2048]

    // input conversions
    xbf_k<<<2048, 256, 0, stream>>>(x, xb);
    wt_k<<<3072, 256, 0, stream>>>(Wq, Wk, Wv, Wo, W1, W2, WqkvT, WoT, W1T, W2T);

    // fused QKV projection (MFMA)
    gemm_qkv_k<<<dim3(12, 32), 256, 0, stream>>>(xb, WqkvT, bq, bk, bv, Qb, Kb, VTb);

    // flash attention -> ctx bf16 [B,S,D]
    attn_mfma_k<<<dim3(BATCH * N_HEADS, SEQ / 64), 256, 0, stream>>>(Qb, Kb, VTb, Ctx);

    // output projection (MFMA)
    gemm_std_k<64, 2, 0, 0><<<dim3(8, 32), 256, 0, stream>>>(Ctx, WoT, bo, AO, 512, 512);

    // h = LN(x + attn_out), fp32 + bf16
    add_ln_k<1><<<4096, 256, 0, stream>>>(x, AO, g1, be1, Hh, Hhb);

    // FFN (MFMA)
    gemm_std_k<128, 4, 1, 1><<<dim3(16, 32), 256, 0, stream>>>(Hhb, W1T, b1, FF1, 2048, 512);
    gemm_std_k<64, 2, 0, 0><<<dim3(8, 32), 256, 0, stream>>>(FF1, W2T, b2, FF2, 512, 2048);

    // out = LN(h + ff)
    add_ln_k<0><<<4096, 256, 0, stream>>>(Hh, FF2, g2, be2, out, (ushort_t*)nullptr);
}

// Round 4
// 260.798 us; speedup vs baseline: 5.8728x; 1.0733x over previous
//
#include <hip/hip_runtime.h>
#include <cmath>

#define D_MODEL 512
#define N_HEADS 8
#define HEAD_DIM 64
#define D_FF 2048
#define SEQ 2048
#define BATCH 2
#define MROWS (BATCH * SEQ) /* 4096 */

typedef __attribute__((ext_vector_type(8))) short short8;
typedef __attribute__((ext_vector_type(4))) float float4v;
typedef unsigned short ushort_t;

static __device__ __forceinline__ ushort_t f2bf(float f) {
    union { float f; unsigned u; } v; v.f = f;
    unsigned r = (v.u + 0x7FFFu + ((v.u >> 16) & 1u)) >> 16;
    return (ushort_t)r;
}

// async global->LDS, 16B per lane; LDS dest = wave-uniform base + lane*16
static __device__ __forceinline__ void gload16(const void* g, void* l) {
    __builtin_amdgcn_global_load_lds(
        (__attribute__((address_space(1))) void*)(unsigned long long)g,
        (__attribute__((address_space(3))) void*)(unsigned)(unsigned long long)l,
        16, 0, 0);
}

// ---------------------------------------------------------------------------
// x fp32 -> bf16 (same [M][K] layout)
// ---------------------------------------------------------------------------
__global__ __launch_bounds__(256) void xbf_k(const float* __restrict__ x,
                                             ushort_t* __restrict__ xb)
{
    int i = blockIdx.x * 256 + threadIdx.x;
    float4 f = ((const float4*)x)[i];
    ushort4 o;
    o.x = f2bf(f.x); o.y = f2bf(f.y); o.z = f2bf(f.z); o.w = f2bf(f.w);
    ((ushort4*)xb)[i] = o;
}

// ---------------------------------------------------------------------------
// Weight transpose+convert: W[K][N] fp32 -> WT[N][K] bf16, 32x32 LDS tiles.
// ---------------------------------------------------------------------------
__global__ __launch_bounds__(256) void wt_k(
    const float* __restrict__ Wq, const float* __restrict__ Wk,
    const float* __restrict__ Wv, const float* __restrict__ Wo,
    const float* __restrict__ W1, const float* __restrict__ W2,
    ushort_t* __restrict__ WqkvT, ushort_t* __restrict__ WoT,
    ushort_t* __restrict__ W1T, ushort_t* __restrict__ W2T)
{
    int tile = blockIdx.x;                 // 0..3071
    const float* src; ushort_t* dst; int Kd, Nd, tloc;
    if (tile < 1024) {
        int wsel = tile >> 8; tloc = tile & 255; Kd = 512; Nd = 512;
        if (wsel == 0)      { src = Wq; dst = WqkvT; }
        else if (wsel == 1) { src = Wk; dst = WqkvT + (size_t)512 * 512; }
        else if (wsel == 2) { src = Wv; dst = WqkvT + (size_t)1024 * 512; }
        else                { src = Wo; dst = WoT; }
    } else if (tile < 2048) { tloc = tile - 1024; Kd = 512;  Nd = 2048; src = W1; dst = W1T; }
    else                    { tloc = tile - 2048; Kd = 2048; Nd = 512;  src = W2; dst = W2T; }
    int tn = Nd >> 5;
    int k0 = (tloc / tn) << 5, n0 = (tloc % tn) << 5;
    __shared__ float tl[32][33];
    int c = threadIdx.x & 31, r = threadIdx.x >> 5;
    #pragma unroll
    for (int i = 0; i < 4; ++i)
        tl[r + i * 8][c] = src[(size_t)(k0 + r + i * 8) * Nd + n0 + c];
    __syncthreads();
    #pragma unroll
    for (int i = 0; i < 4; ++i)
        dst[(size_t)(n0 + r + i * 8) * Kd + k0 + c] = f2bf(tl[c][r + i * 8]);
}

// ---------------------------------------------------------------------------
// MFMA bf16 GEMM core (m97 recipe), unchanged from round 3.
// ---------------------------------------------------------------------------
template <int BN, int MT>
__device__ __forceinline__ void gemm_core(
    const ushort_t* __restrict__ A, const ushort_t* __restrict__ BT,
    int K, int m0, int n0, float4v (&acc)[MT][4])
{
    __shared__ ushort_t As[128 * 32];
    __shared__ ushort_t Bs[BN * 32];

    const int t = threadIdx.x;
    const int w = t >> 6;
    const int lane = t & 63;
    const int l16 = lane & 15;
    const int quad = lane >> 4;
    constexpr int WCOLS = (BN == 128) ? 2 : 1;
    const int mbase = (w / WCOLS) * (MT * 16);
    const int nbase = (w % WCOLS) * 64;
    const int lr = lane >> 2;
    const int lc = (lane & 3) * 8;

    for (int k0 = 0; k0 < K; k0 += 32) {
        __syncthreads();
        for (int c = w; c < 8; c += 4)
            gload16(A + (size_t)(m0 + c * 16 + lr) * K + k0 + lc, &As[c * 512]);
        for (int c = w; c < BN / 16; c += 4)
            gload16(BT + (size_t)(n0 + c * 16 + lr) * K + k0 + lc, &Bs[c * 512]);
        __syncthreads();

        short8 af[MT], bfr[4];
        #pragma unroll
        for (int mt = 0; mt < MT; ++mt)
            af[mt] = *(const short8*)&As[(mbase + mt * 16 + l16) * 32 + quad * 8];
        #pragma unroll
        for (int nt = 0; nt < 4; ++nt)
            bfr[nt] = *(const short8*)&Bs[(nbase + nt * 16 + l16) * 32 + quad * 8];
        #pragma unroll
        for (int mt = 0; mt < MT; ++mt)
            #pragma unroll
            for (int nt = 0; nt < 4; ++nt)
                acc[mt][nt] = __builtin_amdgcn_mfma_f32_16x16x32_bf16(
                    af[mt], bfr[nt], acc[mt][nt], 0, 0, 0);
    }
}

// ---------------------------------------------------------------------------
// Standard GEMM: out = A @ BT^T + bias, fp32 or bf16 out, optional ReLU.
// ---------------------------------------------------------------------------
template <int BN, int MT, int BF16OUT, int RELU>
__global__ __launch_bounds__(256) void gemm_std_k(
    const ushort_t* __restrict__ A, const ushort_t* __restrict__ BT,
    const float* __restrict__ bias, void* __restrict__ Cv, int N, int K)
{
    const int m0 = blockIdx.y * 128;
    const int n0 = blockIdx.x * BN;
    float4v acc[MT][4];
    #pragma unroll
    for (int mt = 0; mt < MT; ++mt)
        #pragma unroll
        for (int nt = 0; nt < 4; ++nt)
            acc[mt][nt] = (float4v){0.f, 0.f, 0.f, 0.f};
    gemm_core<BN, MT>(A, BT, K, m0, n0, acc);

    const int t = threadIdx.x;
    const int w = t >> 6, lane = t & 63, l16 = lane & 15, quad = lane >> 4;
    constexpr int WCOLS = (BN == 128) ? 2 : 1;
    const int mbase = (w / WCOLS) * (MT * 16);
    const int nbase = (w % WCOLS) * 64;
    #pragma unroll
    for (int mt = 0; mt < MT; ++mt) {
        #pragma unroll
        for (int nt = 0; nt < 4; ++nt) {
            int gcol = n0 + nbase + nt * 16 + l16;
            float b = bias[gcol];
            #pragma unroll
            for (int r = 0; r < 4; ++r) {
                int grow = m0 + mbase + mt * 16 + quad * 4 + r;
                float v = acc[mt][nt][r] + b;
                if (RELU) v = fmaxf(v, 0.f);
                if (BF16OUT) ((ushort_t*)Cv)[(size_t)grow * N + gcol] = f2bf(v);
                else         ((float*)Cv)[(size_t)grow * N + gcol] = v;
            }
        }
    }
}

// ---------------------------------------------------------------------------
// Fused QKV GEMM. Q scale folds 1/sqrt(64) AND log2(e) (softmax uses exp2).
// ---------------------------------------------------------------------------
__global__ __launch_bounds__(256) void gemm_qkv_k(
    const ushort_t* __restrict__ A, const ushort_t* __restrict__ BT,
    const float* __restrict__ bq, const float* __restrict__ bk,
    const float* __restrict__ bv,
    ushort_t* __restrict__ Qb, ushort_t* __restrict__ Kb,
    ushort_t* __restrict__ VTb)
{
    const int m0 = blockIdx.y * 128;
    const int n0 = blockIdx.x * 128;
    float4v acc[4][4];
    #pragma unroll
    for (int mt = 0; mt < 4; ++mt)
        #pragma unroll
        for (int nt = 0; nt < 4; ++nt)
            acc[mt][nt] = (float4v){0.f, 0.f, 0.f, 0.f};
    gemm_core<128, 4>(A, BT, 512, m0, n0, acc);

    const int t = threadIdx.x;
    const int w = t >> 6, lane = t & 63, l16 = lane & 15, quad = lane >> 4;
    const int mbase = (w >> 1) * 64;
    const int nbase = (w & 1) * 64;
    const int tsel = n0 >> 9;
    const float* bias = (tsel == 0) ? bq : (tsel == 1) ? bk : bv;
    const float scl = (tsel == 0) ? 0.18033688f : 1.0f;  // 0.125 * log2(e)
    ushort_t* dst = (tsel == 0) ? Qb : Kb;

    #pragma unroll
    for (int mt = 0; mt < 4; ++mt) {
        #pragma unroll
        for (int nt = 0; nt < 4; ++nt) {
            int gcol = n0 + nbase + nt * 16 + l16;
            int lcol = gcol - (tsel << 9);
            int h = lcol >> 6, dh = lcol & 63;
            float b = bias[lcol];
            #pragma unroll
            for (int r = 0; r < 4; ++r) {
                int grow = m0 + mbase + mt * 16 + quad * 4 + r;
                int bb = grow >> 11, s = grow & 2047;
                float v = (acc[mt][nt][r] + b) * scl;
                if (tsel < 2)
                    dst[(((size_t)(bb * N_HEADS + h)) * SEQ + s) * HEAD_DIM + dh] = f2bf(v);
                else
                    VTb[(((size_t)(bb * N_HEADS + h)) * HEAD_DIM + dh) * SEQ + s] = f2bf(v);
            }
        }
    }
}

// ---------------------------------------------------------------------------
// bf16 MFMA flash attention v3: fixed-max softmax (exp2 domain, M2=10*log2e),
// deferred l-reduction, split-K x2 -> unnormalized fp32 partials.
// Grid (16 bh, 32 qt, 2 ks). Block 256 thr = 4 waves x 16 q-rows.
// Opart: [ks][bh][q][64] fp32 (unnormalized); Lpart: [ks][bh][q] fp32.
// ---------------------------------------------------------------------------
__global__ __launch_bounds__(256) void attn_mfma_k(
    const ushort_t* __restrict__ Qg, const ushort_t* __restrict__ Kg,
    const ushort_t* __restrict__ VTg,
    float* __restrict__ Opart, float* __restrict__ Lpart)
{
    __shared__ __align__(16) ushort_t Ks[64 * 72];
    __shared__ __align__(16) ushort_t Vs[64 * 72];
    __shared__ __align__(16) ushort_t Ps[4][16 * 76];  // stride 76: conflict-free writes

    const int bh = blockIdx.x;
    const int q0 = blockIdx.y * 64;
    const int ks = blockIdx.z;
    const int t = threadIdx.x;
    const int w = t >> 6;
    const int lane = t & 63;
    const int l16 = lane & 15;
    const int quad = lane >> 4;
    const int qbase = q0 + w * 16;
    const float M2 = 14.4269504f;   // 10 * log2(e); scores pre-scaled by log2(e)/8

    short8 aq[2];
    {
        const ushort_t* qp = Qg + ((size_t)bh * SEQ + qbase + l16) * HEAD_DIM + quad * 8;
        aq[0] = *(const short8*)(qp);
        aq[1] = *(const short8*)(qp + 32);
    }

    float4v o[4] = {};
    float l_acc[4] = {0.f, 0.f, 0.f, 0.f};

    for (int kt = 0; kt < 16; ++kt) {
        const int kbase = ks * 1024 + kt * 64;
        __syncthreads();
        #pragma unroll
        for (int lit = 0; lit < 2; ++lit) {
            int flat = lit * 256 + t;
            int row = flat >> 3;
            int c0 = (flat & 7) * 8;
            *(short8*)&Ks[row * 72 + c0] =
                *(const short8*)(Kg + ((size_t)bh * SEQ + kbase + row) * HEAD_DIM + c0);
            *(short8*)&Vs[row * 72 + c0] =
                *(const short8*)(VTg + ((size_t)bh * HEAD_DIM + row) * SEQ + kbase + c0);
        }
        __syncthreads();

        float4v s[4];
        #pragma unroll
        for (int nt = 0; nt < 4; ++nt) s[nt] = (float4v){0.f, 0.f, 0.f, 0.f};
        #pragma unroll
        for (int c = 0; c < 2; ++c) {
            #pragma unroll
            for (int nt = 0; nt < 4; ++nt) {
                short8 bk8 = *(const short8*)&Ks[(nt * 16 + l16) * 72 + c * 32 + quad * 8];
                s[nt] = __builtin_amdgcn_mfma_f32_16x16x32_bf16(aq[c], bk8, s[nt], 0, 0, 0);
            }
        }

        // fixed-max softmax: p = 2^(s - M2); l accumulated per-lane, reduced at end
        #pragma unroll
        for (int nt = 0; nt < 4; ++nt) {
            #pragma unroll
            for (int r = 0; r < 4; ++r) {
                float p = exp2f(s[nt][r] - M2);
                s[nt][r] = p;
                l_acc[r] += p;
            }
        }

        // P -> per-wave LDS [qrow][key], stride 76
        #pragma unroll
        for (int nt = 0; nt < 4; ++nt)
            #pragma unroll
            for (int r = 0; r < 4; ++r)
                Ps[w][(quad * 4 + r) * 76 + nt * 16 + l16] = f2bf(s[nt][r]);
        asm volatile("s_waitcnt lgkmcnt(0)" ::: "memory");  // wave-private Ps visible

        #pragma unroll
        for (int c = 0; c < 2; ++c) {
            short8 ap = *(const short8*)&Ps[w][l16 * 76 + c * 32 + quad * 8];
            #pragma unroll
            for (int dt = 0; dt < 4; ++dt) {
                short8 bv8 = *(const short8*)&Vs[(dt * 16 + l16) * 72 + c * 32 + quad * 8];
                o[dt] = __builtin_amdgcn_mfma_f32_16x16x32_bf16(ap, bv8, o[dt], 0, 0, 0);
            }
        }
    }

    // epilogue: reduce l across the 16 lanes of each row group; write partials
    const size_t pbase = ((size_t)(ks * 16 + bh)) * SEQ;
    #pragma unroll
    for (int r = 0; r < 4; ++r) {
        float L = l_acc[r];
        #pragma unroll
        for (int msk = 1; msk < 16; msk <<= 1) L += __shfl_xor(L, msk);
        int qrow = qbase + quad * 4 + r;
        if (l16 == 0) Lpart[pbase + qrow] = L;
        #pragma unroll
        for (int dt = 0; dt < 4; ++dt)
            Opart[(pbase + qrow) * HEAD_DIM + dt * 16 + l16] = o[dt][r];
    }
}

// ---------------------------------------------------------------------------
// Combine split-K attention partials: ctx = (Oa+Ob)/(la+lb), bf16 [B,S,D].
// ---------------------------------------------------------------------------
__global__ __launch_bounds__(256) void attn_comb_k(
    const float* __restrict__ Op, const float* __restrict__ Lp,
    ushort_t* __restrict__ ctx)
{
    int g = blockIdx.x * 256 + threadIdx.x;      // 0..524287
    int d4 = g & 15;
    int q  = (g >> 4) & 2047;
    int bh = g >> 15;
    size_t rowa = ((size_t)bh * SEQ + q) * HEAD_DIM;
    size_t rowb = ((size_t)(16 + bh) * SEQ + q) * HEAD_DIM;
    float4 a = ((const float4*)(Op + rowa))[d4];
    float4 b = ((const float4*)(Op + rowb))[d4];
    float inv = 1.0f / (Lp[bh * SEQ + q] + Lp[16 * SEQ * 16 / 16 * 2048 / 2048 * 0 + 32768 + bh * SEQ + q]);
    ushort4 o4;
    o4.x = f2bf((a.x + b.x) * inv);
    o4.y = f2bf((a.y + b.y) * inv);
    o4.z = f2bf((a.z + b.z) * inv);
    o4.w = f2bf((a.w + b.w) * inv);
    int bb = bh >> 3, hh = bh & 7;
    *(ushort4*)&ctx[((size_t)(bb * SEQ + q)) * D_MODEL + hh * HEAD_DIM + d4 * 4] = o4;
}

// ---------------------------------------------------------------------------
// Residual + LayerNorm; optional bf16 copy of the output.
// ---------------------------------------------------------------------------
template <int WRITE_BF>
__global__ __launch_bounds__(256) void add_ln_k(
    const float* __restrict__ X, const float* __restrict__ Y,
    const float* __restrict__ gam, const float* __restrict__ bet,
    float* __restrict__ O, ushort_t* __restrict__ Ob)
{
    const int row = blockIdx.x;
    const int t = threadIdx.x;
    const float* x = X + (size_t)row * D_MODEL;
    const float* y = Y + (size_t)row * D_MODEL;

    float v0 = x[t] + y[t];
    float v1 = x[t + 256] + y[t + 256];
    float s = v0 + v1;
    float ss = v0 * v0 + v1 * v1;
    #pragma unroll
    for (int off = 32; off > 0; off >>= 1) {
        s  += __shfl_down(s, off);
        ss += __shfl_down(ss, off);
    }
    __shared__ float sb[4], ssb[4];
    if ((t & 63) == 0) { sb[t >> 6] = s; ssb[t >> 6] = ss; }
    __syncthreads();
    float S  = sb[0] + sb[1] + sb[2] + sb[3];
    float SS = ssb[0] + ssb[1] + ssb[2] + ssb[3];
    float mu  = S * (1.0f / D_MODEL);
    float var = SS * (1.0f / D_MODEL) - mu * mu;
    float inv = rsqrtf(var + 1e-5f);
    float o0 = (v0 - mu) * inv * gam[t] + bet[t];
    float o1 = (v1 - mu) * inv * gam[t + 256] + bet[t + 256];
    O[(size_t)row * D_MODEL + t]       = o0;
    O[(size_t)row * D_MODEL + t + 256] = o1;
    if (WRITE_BF) {
        Ob[(size_t)row * D_MODEL + t]       = f2bf(o0);
        Ob[(size_t)row * D_MODEL + t + 256] = f2bf(o1);
    }
}

// ---------------------------------------------------------------------------
extern "C" void kernel_launch(void* const* d_in, const int* in_sizes, int n_in,
                              void* d_out, int out_size, void* d_ws, size_t ws_size,
                              hipStream_t stream)
{
    const float* x   = (const float*)d_in[0];
    const float* Wq  = (const float*)d_in[1];
    const float* bq  = (const float*)d_in[2];
    const float* Wk  = (const float*)d_in[3];
    const float* bk  = (const float*)d_in[4];
    const float* Wv  = (const float*)d_in[5];
    const float* bv  = (const float*)d_in[6];
    const float* Wo  = (const float*)d_in[7];
    const float* bo  = (const float*)d_in[8];
    const float* W1  = (const float*)d_in[9];
    const float* b1  = (const float*)d_in[10];
    const float* W2  = (const float*)d_in[11];
    const float* b2  = (const float*)d_in[12];
    const float* g1  = (const float*)d_in[13];
    const float* be1 = (const float*)d_in[14];
    const float* g2  = (const float*)d_in[15];
    const float* be2 = (const float*)d_in[16];
    float* out = (float*)d_out;
    float* ws  = (float*)d_ws;

    // float-unit offsets (total 15,204,352 floats = 60.8 MB)
    ushort_t* xb    = (ushort_t*)(ws);               // [4096][512] bf16
    ushort_t* WqkvT = (ushort_t*)(ws + 1048576);     // [1536][512] bf16
    ushort_t* WoT   = (ushort_t*)(ws + 1441792);     // [512][512]
    ushort_t* W1T   = (ushort_t*)(ws + 1572864);     // [2048][512]
    ushort_t* W2T   = (ushort_t*)(ws + 2097152);     // [512][2048]
    ushort_t* Qb    = (ushort_t*)(ws + 2621440);     // [16][2048][64]
    ushort_t* Kb    = (ushort_t*)(ws + 3670016);
    ushort_t* VTb   = (ushort_t*)(ws + 4718592);     // [16][64][2048]
    ushort_t* Ctx   = (ushort_t*)(ws + 5767168);     // [4096][512] bf16
    float*    Lpart = ws + 6815744;                  // [2][16][2048] (dead before Hh)
    float*    Opart = ws + 11010048;                 // [2][16][2048][64] (FF1 slot, disjoint lifetime)
    float*    AO    = ws + 2621440;                  // fp32, over Qb+Kb (dead after combine)
    ushort_t* Hhb   = (ushort_t*)(ws + 4718592);     // bf16, over VTb (dead)
    float*    Hh    = ws + 6815744;                  // fp32 [4096][512]
    float*    FF2   = ws + 8912896;                  // fp32 [4096][512]
    ushort_t* FF1   = (ushort_t*)(ws + 11010048);    // bf16 [4096][2048]

    // input conversions
    xbf_k<<<2048, 256, 0, stream>>>(x, xb);
    wt_k<<<3072, 256, 0, stream>>>(Wq, Wk, Wv, Wo, W1, W2, WqkvT, WoT, W1T, W2T);

    // fused QKV projection (MFMA); Q scaled by 0.125*log2(e)
    gemm_qkv_k<<<dim3(12, 32), 256, 0, stream>>>(xb, WqkvT, bq, bk, bv, Qb, Kb, VTb);

    // flash attention split-K -> partials, then combine -> ctx bf16
    attn_mfma_k<<<dim3(16, 32, 2), 256, 0, stream>>>(Qb, Kb, VTb, Opart, Lpart);
    attn_comb_k<<<2048, 256, 0, stream>>>(Opart, Lpart, Ctx);

    // output projection (MFMA)
    gemm_std_k<64, 2, 0, 0><<<dim3(8, 32), 256, 0, stream>>>(Ctx, WoT, bo, AO, 512, 512);

    // h = LN(x + attn_out), fp32 + bf16
    add_ln_k<1><<<4096, 256, 0, stream>>>(x, AO, g1, be1, Hh, Hhb);

    // FFN (MFMA)
    gemm_std_k<128, 4, 1, 1><<<dim3(16, 32), 256, 0, stream>>>(Hhb, W1T, b1, FF1, 2048, 512);
    gemm_std_k<64, 2, 0, 0><<<dim3(8, 32), 256, 0, stream>>>(FF1, W2T, b2, FF2, 512, 2048);

    // out = LN(h + ff)
    add_ln_k<0><<<4096, 256, 0, stream>>>(Hh, FF2, g2, be2, out, (ushort_t*)nullptr);
}

// Round 5
// 232.686 us; speedup vs baseline: 6.5823x; 1.1208x over previous
//
#include <hip/hip_runtime.h>
#include <cmath>

#define D_MODEL 512
#define N_HEADS 8
#define HEAD_DIM 64
#define D_FF 2048
#define SEQ 2048
#define BATCH 2
#define MROWS (BATCH * SEQ) /* 4096 */

typedef __attribute__((ext_vector_type(8))) short short8;
typedef __attribute__((ext_vector_type(4))) float float4v;
typedef unsigned short ushort_t;

static __device__ __forceinline__ ushort_t f2bf(float f) {
    union { float f; unsigned u; } v; v.f = f;
    unsigned r = (v.u + 0x7FFFu + ((v.u >> 16) & 1u)) >> 16;
    return (ushort_t)r;
}
static __device__ __forceinline__ ushort_t f2bf_trunc(float f) {
    union { float f; unsigned u; } v; v.f = f;
    return (ushort_t)(v.u >> 16);
}

// async global->LDS, 16B per lane; LDS dest = wave-uniform base + lane*16
static __device__ __forceinline__ void gload16(const void* g, void* l) {
    __builtin_amdgcn_global_load_lds(
        (__attribute__((address_space(1))) void*)(unsigned long long)g,
        (__attribute__((address_space(3))) void*)(unsigned)(unsigned long long)l,
        16, 0, 0);
}

// ---------------------------------------------------------------------------
// x fp32 -> bf16
// ---------------------------------------------------------------------------
__global__ __launch_bounds__(256) void xbf_k(const float* __restrict__ x,
                                             ushort_t* __restrict__ xb)
{
    int i = blockIdx.x * 256 + threadIdx.x;
    float4 f = ((const float4*)x)[i];
    ushort4 o;
    o.x = f2bf(f.x); o.y = f2bf(f.y); o.z = f2bf(f.z); o.w = f2bf(f.w);
    ((ushort4*)xb)[i] = o;
}

// ---------------------------------------------------------------------------
// Weight transpose+convert: W[K][N] fp32 -> WT[N][K] bf16, 32x32 LDS tiles.
// ---------------------------------------------------------------------------
__global__ __launch_bounds__(256) void wt_k(
    const float* __restrict__ Wq, const float* __restrict__ Wk,
    const float* __restrict__ Wv, const float* __restrict__ Wo,
    const float* __restrict__ W1, const float* __restrict__ W2,
    ushort_t* __restrict__ WqkvT, ushort_t* __restrict__ WoT,
    ushort_t* __restrict__ W1T, ushort_t* __restrict__ W2T)
{
    int tile = blockIdx.x;                 // 0..3071
    const float* src; ushort_t* dst; int Kd, Nd, tloc;
    if (tile < 1024) {
        int wsel = tile >> 8; tloc = tile & 255; Kd = 512; Nd = 512;
        if (wsel == 0)      { src = Wq; dst = WqkvT; }
        else if (wsel == 1) { src = Wk; dst = WqkvT + (size_t)512 * 512; }
        else if (wsel == 2) { src = Wv; dst = WqkvT + (size_t)1024 * 512; }
        else                { src = Wo; dst = WoT; }
    } else if (tile < 2048) { tloc = tile - 1024; Kd = 512;  Nd = 2048; src = W1; dst = W1T; }
    else                    { tloc = tile - 2048; Kd = 2048; Nd = 512;  src = W2; dst = W2T; }
    int tn = Nd >> 5;
    int k0 = (tloc / tn) << 5, n0 = (tloc % tn) << 5;
    __shared__ float tl[32][33];
    int c = threadIdx.x & 31, r = threadIdx.x >> 5;
    #pragma unroll
    for (int i = 0; i < 4; ++i)
        tl[r + i * 8][c] = src[(size_t)(k0 + r + i * 8) * Nd + n0 + c];
    __syncthreads();
    #pragma unroll
    for (int i = 0; i < 4; ++i)
        dst[(size_t)(n0 + r + i * 8) * Kd + k0 + c] = f2bf(tl[c][r + i * 8]);
}

// ---------------------------------------------------------------------------
// MFMA bf16 GEMM core: C[BM x BN] += A[m0.., kbase..kbase+Klen) @ BT^T.
// 4 waves in WROWSxWCOLS grid; wave tile (MT*16) x (NT*16). BK=32.
// ---------------------------------------------------------------------------
template <int BM, int BN, int WCOLS, int MT, int NT>
__device__ __forceinline__ void gemm_core(
    const ushort_t* __restrict__ A, const ushort_t* __restrict__ BT,
    int K, int kbase, int Klen, int m0, int n0, float4v (&acc)[MT][NT])
{
    __shared__ ushort_t As[BM * 32];
    __shared__ ushort_t Bs[BN * 32];

    const int t = threadIdx.x;
    const int w = t >> 6;
    const int lane = t & 63;
    const int l16 = lane & 15;
    const int quad = lane >> 4;
    const int mbase = (w / WCOLS) * (MT * 16);
    const int nbase = (w % WCOLS) * (NT * 16);
    const int lr = lane >> 2;
    const int lc = (lane & 3) * 8;

    for (int k0 = kbase; k0 < kbase + Klen; k0 += 32) {
        __syncthreads();
        for (int c = w; c < BM / 16; c += 4)
            gload16(A + (size_t)(m0 + c * 16 + lr) * K + k0 + lc, &As[c * 512]);
        for (int c = w; c < BN / 16; c += 4)
            gload16(BT + (size_t)(n0 + c * 16 + lr) * K + k0 + lc, &Bs[c * 512]);
        __syncthreads();

        short8 af[MT], bfr[NT];
        #pragma unroll
        for (int mt = 0; mt < MT; ++mt)
            af[mt] = *(const short8*)&As[(mbase + mt * 16 + l16) * 32 + quad * 8];
        #pragma unroll
        for (int nt = 0; nt < NT; ++nt)
            bfr[nt] = *(const short8*)&Bs[(nbase + nt * 16 + l16) * 32 + quad * 8];
        #pragma unroll
        for (int mt = 0; mt < MT; ++mt)
            #pragma unroll
            for (int nt = 0; nt < NT; ++nt)
                acc[mt][nt] = __builtin_amdgcn_mfma_f32_16x16x32_bf16(
                    af[mt], bfr[nt], acc[mt][nt], 0, 0, 0);
    }
}

// ---------------------------------------------------------------------------
// Standard GEMM. MODE: 0 = fp32 + bias; 1 = bf16 + bias + ReLU;
//                 2 = fp32 raw partial (no bias; dst += z*zstride) for split-K.
// ---------------------------------------------------------------------------
template <int BM, int BN, int WCOLS, int MT, int NT, int MODE>
__global__ __launch_bounds__(256) void gemm_std_k(
    const ushort_t* __restrict__ A, const ushort_t* __restrict__ BT,
    const float* __restrict__ bias, void* __restrict__ Cv,
    int N, int K, int Klen, size_t zstride)
{
    const int m0 = blockIdx.y * BM;
    const int n0 = blockIdx.x * BN;
    const int kbase = blockIdx.z * Klen;
    float4v acc[MT][NT];
    #pragma unroll
    for (int mt = 0; mt < MT; ++mt)
        #pragma unroll
        for (int nt = 0; nt < NT; ++nt)
            acc[mt][nt] = (float4v){0.f, 0.f, 0.f, 0.f};
    gemm_core<BM, BN, WCOLS, MT, NT>(A, BT, K, kbase, Klen, m0, n0, acc);

    const int t = threadIdx.x;
    const int w = t >> 6, lane = t & 63, l16 = lane & 15, quad = lane >> 4;
    const int mbase = (w / WCOLS) * (MT * 16);
    const int nbase = (w % WCOLS) * (NT * 16);
    float* Cf = (float*)Cv + blockIdx.z * zstride;
    #pragma unroll
    for (int mt = 0; mt < MT; ++mt) {
        #pragma unroll
        for (int nt = 0; nt < NT; ++nt) {
            int gcol = n0 + nbase + nt * 16 + l16;
            float b = (MODE == 2) ? 0.f : bias[gcol];
            #pragma unroll
            for (int r = 0; r < 4; ++r) {
                int grow = m0 + mbase + mt * 16 + quad * 4 + r;
                float v = acc[mt][nt][r] + b;
                if (MODE == 1) v = fmaxf(v, 0.f);
                if (MODE == 1) ((ushort_t*)Cv)[(size_t)grow * N + gcol] = f2bf(v);
                else           Cf[(size_t)grow * N + gcol] = v;
            }
        }
    }
}

// ---------------------------------------------------------------------------
// Fused QKV GEMM (BM=64). Q scale folds 1/sqrt(64) and log2(e).
// ---------------------------------------------------------------------------
__global__ __launch_bounds__(256) void gemm_qkv_k(
    const ushort_t* __restrict__ A, const ushort_t* __restrict__ BT,
    const float* __restrict__ bq, const float* __restrict__ bk,
    const float* __restrict__ bv,
    ushort_t* __restrict__ Qb, ushort_t* __restrict__ Kb,
    ushort_t* __restrict__ VTb)
{
    const int m0 = blockIdx.y * 64;
    const int n0 = blockIdx.x * 128;
    float4v acc[2][4];
    #pragma unroll
    for (int mt = 0; mt < 2; ++mt)
        #pragma unroll
        for (int nt = 0; nt < 4; ++nt)
            acc[mt][nt] = (float4v){0.f, 0.f, 0.f, 0.f};
    gemm_core<64, 128, 2, 2, 4>(A, BT, 512, 0, 512, m0, n0, acc);

    const int t = threadIdx.x;
    const int w = t >> 6, lane = t & 63, l16 = lane & 15, quad = lane >> 4;
    const int mbase = (w >> 1) * 32;
    const int nbase = (w & 1) * 64;
    const int tsel = n0 >> 9;                       // 0=Q 1=K 2=V (block-uniform)
    const float* bias = (tsel == 0) ? bq : (tsel == 1) ? bk : bv;
    const float scl = (tsel == 0) ? 0.18033688f : 1.0f;  // 0.125 * log2(e)
    ushort_t* dst = (tsel == 0) ? Qb : Kb;

    #pragma unroll
    for (int mt = 0; mt < 2; ++mt) {
        #pragma unroll
        for (int nt = 0; nt < 4; ++nt) {
            int gcol = n0 + nbase + nt * 16 + l16;
            int lcol = gcol - (tsel << 9);
            int h = lcol >> 6, dh = lcol & 63;
            float b = bias[lcol];
            #pragma unroll
            for (int r = 0; r < 4; ++r) {
                int grow = m0 + mbase + mt * 16 + quad * 4 + r;
                int bb = grow >> 11, s = grow & 2047;
                float v = (acc[mt][nt][r] + b) * scl;
                if (tsel < 2)
                    dst[(((size_t)(bb * N_HEADS + h)) * SEQ + s) * HEAD_DIM + dh] = f2bf(v);
                else
                    VTb[(((size_t)(bb * N_HEADS + h)) * HEAD_DIM + dh) * SEQ + s] = f2bf(v);
            }
        }
    }
}

// ---------------------------------------------------------------------------
// bf16 MFMA flash attention: fixed-max softmax (exp2 domain), split-K x2,
// unnormalized fp32 partials. Grid (16 bh, 32 qt, 2 ks).
// ---------------------------------------------------------------------------
__global__ __launch_bounds__(256) void attn_mfma_k(
    const ushort_t* __restrict__ Qg, const ushort_t* __restrict__ Kg,
    const ushort_t* __restrict__ VTg,
    float* __restrict__ Opart, float* __restrict__ Lpart)
{
    __shared__ __align__(16) ushort_t Ks[64 * 72];
    __shared__ __align__(16) ushort_t Vs[64 * 72];
    __shared__ __align__(16) ushort_t Ps[4][16 * 76];

    const int bh = blockIdx.x;
    const int q0 = blockIdx.y * 64;
    const int ks = blockIdx.z;
    const int t = threadIdx.x;
    const int w = t >> 6;
    const int lane = t & 63;
    const int l16 = lane & 15;
    const int quad = lane >> 4;
    const int qbase = q0 + w * 16;
    const float M2 = 14.4269504f;   // 10 * log2(e); scores pre-scaled by log2(e)/8

    short8 aq[2];
    {
        const ushort_t* qp = Qg + ((size_t)bh * SEQ + qbase + l16) * HEAD_DIM + quad * 8;
        aq[0] = *(const short8*)(qp);
        aq[1] = *(const short8*)(qp + 32);
    }

    float4v o[4] = {};
    float l_acc[4] = {0.f, 0.f, 0.f, 0.f};

    for (int kt = 0; kt < 16; ++kt) {
        const int kbase = ks * 1024 + kt * 64;
        __syncthreads();
        #pragma unroll
        for (int lit = 0; lit < 2; ++lit) {
            int flat = lit * 256 + t;
            int row = flat >> 3;
            int c0 = (flat & 7) * 8;
            *(short8*)&Ks[row * 72 + c0] =
                *(const short8*)(Kg + ((size_t)bh * SEQ + kbase + row) * HEAD_DIM + c0);
            *(short8*)&Vs[row * 72 + c0] =
                *(const short8*)(VTg + ((size_t)bh * HEAD_DIM + row) * SEQ + kbase + c0);
        }
        __syncthreads();

        float4v s[4];
        #pragma unroll
        for (int nt = 0; nt < 4; ++nt) s[nt] = (float4v){0.f, 0.f, 0.f, 0.f};
        #pragma unroll
        for (int c = 0; c < 2; ++c) {
            #pragma unroll
            for (int nt = 0; nt < 4; ++nt) {
                short8 bk8 = *(const short8*)&Ks[(nt * 16 + l16) * 72 + c * 32 + quad * 8];
                s[nt] = __builtin_amdgcn_mfma_f32_16x16x32_bf16(aq[c], bk8, s[nt], 0, 0, 0);
            }
        }

        #pragma unroll
        for (int nt = 0; nt < 4; ++nt) {
            #pragma unroll
            for (int r = 0; r < 4; ++r) {
                float p = exp2f(s[nt][r] - M2);
                s[nt][r] = p;
                l_acc[r] += p;
            }
        }

        #pragma unroll
        for (int nt = 0; nt < 4; ++nt)
            #pragma unroll
            for (int r = 0; r < 4; ++r)
                Ps[w][(quad * 4 + r) * 76 + nt * 16 + l16] = f2bf_trunc(s[nt][r]);
        asm volatile("s_waitcnt lgkmcnt(0)" ::: "memory");

        #pragma unroll
        for (int c = 0; c < 2; ++c) {
            short8 ap = *(const short8*)&Ps[w][l16 * 76 + c * 32 + quad * 8];
            #pragma unroll
            for (int dt = 0; dt < 4; ++dt) {
                short8 bv8 = *(const short8*)&Vs[(dt * 16 + l16) * 72 + c * 32 + quad * 8];
                o[dt] = __builtin_amdgcn_mfma_f32_16x16x32_bf16(ap, bv8, o[dt], 0, 0, 0);
            }
        }
    }

    const size_t pbase = ((size_t)(ks * 16 + bh)) * SEQ;
    #pragma unroll
    for (int r = 0; r < 4; ++r) {
        float L = l_acc[r];
        #pragma unroll
        for (int msk = 1; msk < 16; msk <<= 1) L += __shfl_xor(L, msk);
        int qrow = qbase + quad * 4 + r;
        if (l16 == 0) Lpart[pbase + qrow] = L;
        #pragma unroll
        for (int dt = 0; dt < 4; ++dt)
            Opart[(pbase + qrow) * HEAD_DIM + dt * 16 + l16] = o[dt][r];
    }
}

// ---------------------------------------------------------------------------
// Combine split-K attention partials: ctx = (Oa+Ob)/(la+lb), bf16 [B,S,D].
// ---------------------------------------------------------------------------
__global__ __launch_bounds__(256) void attn_comb_k(
    const float* __restrict__ Op, const float* __restrict__ Lp,
    ushort_t* __restrict__ ctx)
{
    int g = blockIdx.x * 256 + threadIdx.x;      // 0..524287
    int d4 = g & 15;
    int q  = (g >> 4) & 2047;
    int bh = g >> 15;
    size_t rowa = ((size_t)bh * SEQ + q) * HEAD_DIM;
    size_t rowb = ((size_t)(16 + bh) * SEQ + q) * HEAD_DIM;
    float4 a = ((const float4*)(Op + rowa))[d4];
    float4 b = ((const float4*)(Op + rowb))[d4];
    float inv = 1.0f / (Lp[bh * SEQ + q] + Lp[16 * SEQ + bh * SEQ + q]);
    ushort4 o4;
    o4.x = f2bf((a.x + b.x) * inv);
    o4.y = f2bf((a.y + b.y) * inv);
    o4.z = f2bf((a.z + b.z) * inv);
    o4.w = f2bf((a.w + b.w) * inv);
    int bb = bh >> 3, hh = bh & 7;
    *(ushort4*)&ctx[((size_t)(bb * SEQ + q)) * D_MODEL + hh * HEAD_DIM + d4 * 4] = o4;
}

// ---------------------------------------------------------------------------
// Residual + LayerNorm over split-K partials:
// O[row] = LN(X[row] + P0[row] + P1[row] + bias) * gamma + beta
// ---------------------------------------------------------------------------
template <int WRITE_BF>
__global__ __launch_bounds__(256) void add_ln_k(
    const float* __restrict__ X, const float* __restrict__ P0,
    const float* __restrict__ P1, const float* __restrict__ bias,
    const float* __restrict__ gam, const float* __restrict__ bet,
    float* __restrict__ O, ushort_t* __restrict__ Ob)
{
    const int row = blockIdx.x;
    const int t = threadIdx.x;
    const size_t ro = (size_t)row * D_MODEL;

    float v0 = X[ro + t]       + P0[ro + t]       + P1[ro + t]       + bias[t];
    float v1 = X[ro + t + 256] + P0[ro + t + 256] + P1[ro + t + 256] + bias[t + 256];
    float s = v0 + v1;
    float ss = v0 * v0 + v1 * v1;
    #pragma unroll
    for (int off = 32; off > 0; off >>= 1) {
        s  += __shfl_down(s, off);
        ss += __shfl_down(ss, off);
    }
    __shared__ float sb[4], ssb[4];
    if ((t & 63) == 0) { sb[t >> 6] = s; ssb[t >> 6] = ss; }
    __syncthreads();
    float S  = sb[0] + sb[1] + sb[2] + sb[3];
    float SS = ssb[0] + ssb[1] + ssb[2] + ssb[3];
    float mu  = S * (1.0f / D_MODEL);
    float var = SS * (1.0f / D_MODEL) - mu * mu;
    float inv = rsqrtf(var + 1e-5f);
    float o0 = (v0 - mu) * inv * gam[t] + bet[t];
    float o1 = (v1 - mu) * inv * gam[t + 256] + bet[t + 256];
    O[ro + t]       = o0;
    O[ro + t + 256] = o1;
    if (WRITE_BF) {
        Ob[ro + t]       = f2bf(o0);
        Ob[ro + t + 256] = f2bf(o1);
    }
}

// ---------------------------------------------------------------------------
extern "C" void kernel_launch(void* const* d_in, const int* in_sizes, int n_in,
                              void* d_out, int out_size, void* d_ws, size_t ws_size,
                              hipStream_t stream)
{
    const float* x   = (const float*)d_in[0];
    const float* Wq  = (const float*)d_in[1];
    const float* bq  = (const float*)d_in[2];
    const float* Wk  = (const float*)d_in[3];
    const float* bk  = (const float*)d_in[4];
    const float* Wv  = (const float*)d_in[5];
    const float* bv  = (const float*)d_in[6];
    const float* Wo  = (const float*)d_in[7];
    const float* bo  = (const float*)d_in[8];
    const float* W1  = (const float*)d_in[9];
    const float* b1  = (const float*)d_in[10];
    const float* W2  = (const float*)d_in[11];
    const float* b2  = (const float*)d_in[12];
    const float* g1  = (const float*)d_in[13];
    const float* be1 = (const float*)d_in[14];
    const float* g2  = (const float*)d_in[15];
    const float* be2 = (const float*)d_in[16];
    float* out = (float*)d_out;
    float* ws  = (float*)d_ws;

    // float-unit offsets; total 13,172,736 fl = 52.7 MB, lifetime-overlaid.
    ushort_t* WoT   = (ushort_t*)(ws);               // [512][512] bf16
    ushort_t* W1T   = (ushort_t*)(ws + 131072);      // [2048][512]
    ushort_t* W2T   = (ushort_t*)(ws + 655360);      // [512][2048]
    ushort_t* WqkvT = (ushort_t*)(ws + 1179648);     // [1536][512]
    ushort_t* xb    = (ushort_t*)(ws + 1572864);     // [4096][512] bf16
    ushort_t* Qb    = (ushort_t*)(ws + 2621440);     // [16][2048][64]
    ushort_t* Kb    = (ushort_t*)(ws + 3670016);
    ushort_t* VTb   = (ushort_t*)(ws + 4718592);     // [16][64][2048]
    ushort_t* Ctx   = (ushort_t*)(ws + 5767168);     // [4096][512] bf16
    float*    Lpart = ws + 6815744;                  // [2][16][2048]
    float*    Hh    = ws + 6881280;                  // [4096][512] fp32
    float*    P0    = ws + 8978432;                  // [4096][512] fp32 partial
    float*    P1    = ws + 11075584;                 // [4096][512] fp32 partial
    float*    Opart = ws + 8978432;                  // [2][16][2048][64] (P0+P1 slot, dead before Wo)
    ushort_t* FF1   = (ushort_t*)(ws + 1572864);     // [4096][2048] bf16 (xb..VTb slot, dead by W1)
    ushort_t* Hhb   = (ushort_t*)(ws + 5767168);     // [4096][512] bf16 (Ctx slot, dead after Wo)

    // input conversions
    xbf_k<<<2048, 256, 0, stream>>>(x, xb);
    wt_k<<<3072, 256, 0, stream>>>(Wq, Wk, Wv, Wo, W1, W2, WqkvT, WoT, W1T, W2T);

    // fused QKV projection (MFMA, BM=64): 768 blocks
    gemm_qkv_k<<<dim3(12, 64), 256, 0, stream>>>(xb, WqkvT, bq, bk, bv, Qb, Kb, VTb);

    // flash attention split-K -> partials -> combine
    attn_mfma_k<<<dim3(16, 32, 2), 256, 0, stream>>>(Qb, Kb, VTb, Opart, Lpart);
    attn_comb_k<<<2048, 256, 0, stream>>>(Opart, Lpart, Ctx);

    // output projection: split-K x2, raw fp32 partials (bias folded into LN1)
    gemm_std_k<64, 64, 2, 2, 2, 2><<<dim3(8, 64, 2), 256, 0, stream>>>(
        Ctx, WoT, nullptr, P0, 512, 512, 256, (size_t)MROWS * D_MODEL);

    // h = LN(x + p0 + p1 + bo)
    add_ln_k<1><<<4096, 256, 0, stream>>>(x, P0, P1, bo, g1, be1, Hh, Hhb);

    // FFN up: bf16 + bias + ReLU, 1024 blocks
    gemm_std_k<64, 128, 2, 2, 4, 1><<<dim3(16, 64), 256, 0, stream>>>(
        Hhb, W1T, b1, FF1, 2048, 512, 512, 0);

    // FFN down: split-K x2, raw fp32 partials (bias folded into LN2)
    gemm_std_k<64, 64, 2, 2, 2, 2><<<dim3(8, 64, 2), 256, 0, stream>>>(
        FF1, W2T, nullptr, P0, 512, 2048, 1024, (size_t)MROWS * D_MODEL);

    // out = LN(h + q0 + q1 + b2)
    add_ln_k<0><<<4096, 256, 0, stream>>>(Hh, P0, P1, b2, g2, be2, out, (ushort_t*)nullptr);
}